// Round 10
// baseline (587.985 us; speedup 1.0000x reference)
//
#include <hip/hip_runtime.h>

#define NN 100000
#define NE 1600000
#define DF 32
#define KIT 5
#define MU 0.01f
#define NSLOT 256
#define NV4 (NN * DF / 4)
#define ELLW 36
#define AUXCAP 65536
#define NSLICE 8
#define SLICEN (NN / NSLICE)   // 12500 nodes/slice; colell slice 1.8MB fits XCD L2
#define NSUB 20                // scan-blocks per slice (disjoint segment ranges)
#define NBLKA (NE / 256)       // 6250 blocks in pass A, exactly 256 edges each
#define SEGW 64                // per-block per-slice segment capacity (mean fill 32)
#define INVALID_PK 0xffffffffu // sentinel: rl-field = 32767 >= SLICEN, never valid
#define HALF (NN / 2)          // gather-set phase split: 50000 rows = 3.2MB < 4MB L2

typedef float f32x4 __attribute__((ext_vector_type(4)));
typedef float f32x2 __attribute__((ext_vector_type(2)));

// ---------- one-time ELL build (edge_index is iteration-invariant) ----------

__global__ __launch_bounds__(64) void zero_kernel(int* __restrict__ p, int n) {
    int i = blockIdx.x * blockDim.x + threadIdx.x;
    if (i < n) p[i] = 0;
}

// Pass A: single streaming scan; bin edges into 8 slice-buckets. Zero global
// atomics in the common path. Bucket array aliases S (dead until first agg).
__global__ __launch_bounds__(256) void ell_part_kernel(const int* __restrict__ row,
                                                       const int* __restrict__ col,
                                                       unsigned int* __restrict__ buck,
                                                       int* __restrict__ auxcnt,
                                                       int2* __restrict__ aux) {
    __shared__ int wcnt[4][8];
    __shared__ int woff[4][8];
    __shared__ unsigned int sseg[8][SEGW];       // 2KB staging
    const int t = threadIdx.x;
    const int w = t >> 6;
    const int lane = t & 63;

    ((unsigned int*)sseg)[t] = INVALID_PK;
    ((unsigned int*)sseg)[t + 256] = INVALID_PK;

    const int e = blockIdx.x * 256 + t;          // grid is exactly NE/256
    int b = 8;
    unsigned int packed = INVALID_PK;
    int r = 0, c = 0;
    if (e < NE) {
        r = __builtin_nontemporal_load(&row[e]);
        c = __builtin_nontemporal_load(&col[e]);
        b = r / SLICEN;                          // 0..7
        const int rl = r - b * SLICEN;           // < 12500
        packed = ((unsigned int)rl << 17) | (unsigned int)c;
    }

    int myprefix = 0;
    #pragma unroll
    for (int k = 0; k < 8; ++k) {
        const unsigned long long mk = __ballot(b == k);
        if (lane == 0) wcnt[w][k] = __popcll(mk);
        if (k == b) myprefix = __popcll(mk & ((1ull << lane) - 1ull));
    }
    __syncthreads();
    if (t < 32) {
        const int w2 = t >> 3, k = t & 7;
        int o = 0;
        for (int w3 = 0; w3 < w2; ++w3) o += wcnt[w3][k];
        woff[w2][k] = o;
    }
    __syncthreads();

    if (b < 8) {
        const int pos = woff[w][b] + myprefix;
        if (pos < SEGW) {
            sseg[b][pos] = packed;
        } else {
            const int a = atomicAdd(auxcnt, 1);  // a.s. never
            if (a < AUXCAP) aux[a] = make_int2(r, c);
        }
    }
    __syncthreads();

    #pragma unroll
    for (int k = 0; k < 2; ++k) {
        const int idx = t + k * 256;
        const int bb = idx >> 6;
        const int j = idx & 63;
        buck[((size_t)bb * NBLKA + blockIdx.x) * SEGW + j] = sseg[bb][j];
    }
}

// Pass B1 (count): block (s,j) scans a DISJOINT 1/NSUB range of slice s's
// bucket stream; LDS histogram of all 12500 slice nodes; dump uint16.
__global__ __launch_bounds__(1024) void ell_count_kernel(const unsigned int* __restrict__ buck,
                                                         unsigned short* __restrict__ cnt) {
    __shared__ int hist[SLICEN];                 // 50KB
    const int t = threadIdx.x;
    const int s = blockIdx.x & (NSLICE - 1);
    const int j = blockIdx.x >> 3;               // 0..NSUB-1
    const int lane = t & 63;
    const int wid = t >> 6;                      // 0..15
    const int blo = j * NBLKA / NSUB;
    const int bhi = (j + 1) * NBLKA / NSUB;

    for (int i = t; i < SLICEN; i += 1024) hist[i] = 0;
    __syncthreads();

    const unsigned int* sp = buck + (size_t)s * NBLKA * SEGW;
    int blk = blo + wid;
    unsigned int pk = (blk < bhi) ? sp[(size_t)blk * SEGW + lane] : INVALID_PK;
    for (; blk < bhi; blk += 16) {
        const int nb = blk + 16;
        const unsigned int nx = (nb < bhi) ? sp[(size_t)nb * SEGW + lane] : INVALID_PK;
        const int rl = (int)(pk >> 17);
        if (rl < SLICEN) atomicAdd(&hist[rl], 1);
        pk = nx;
    }
    __syncthreads();
    unsigned short* cp = cnt + ((size_t)s * NSUB + j) * SLICEN;
    for (int i = t; i < SLICEN; i += 1024) cp[i] = (unsigned short)hist[i];
}

// Prefix: per node, exclusive scan of the NSUB counts + degc = total.
__global__ __launch_bounds__(256) void ell_prefix_kernel(unsigned short* __restrict__ cnt,
                                                         int* __restrict__ degc) {
    const int i = blockIdx.x * blockDim.x + threadIdx.x;
    if (i >= NN) return;
    const int s = i / SLICEN;
    const int rl = i - s * SLICEN;
    unsigned short* cp = cnt + (size_t)s * NSUB * SLICEN + rl;
    int base = 0;
    #pragma unroll
    for (int j = 0; j < NSUB; ++j) {
        const int v = cp[(size_t)j * SLICEN];
        cp[(size_t)j * SLICEN] = (unsigned short)base;
        base += v;
    }
    degc[i] = base;
}

// Pass B2 (place): LDS cursors from prefix bases; slot = ldsAtomicAdd.
__global__ __launch_bounds__(1024) void ell_place_kernel(const unsigned int* __restrict__ buck,
                                                         const unsigned short* __restrict__ cnt,
                                                         int* __restrict__ colell,
                                                         int* __restrict__ auxcnt,
                                                         int2* __restrict__ aux) {
    __shared__ int cur[SLICEN];                  // 50KB cursors
    const int t = threadIdx.x;
    const int s = blockIdx.x & (NSLICE - 1);
    const int j = blockIdx.x >> 3;
    const int lane = t & 63;
    const int wid = t >> 6;
    const int blo = j * NBLKA / NSUB;
    const int bhi = (j + 1) * NBLKA / NSUB;

    const unsigned short* cp = cnt + ((size_t)s * NSUB + j) * SLICEN;
    for (int i = t; i < SLICEN; i += 1024) cur[i] = (int)cp[i];
    __syncthreads();

    const unsigned int* sp = buck + (size_t)s * NBLKA * SEGW;
    int blk = blo + wid;
    unsigned int pk = (blk < bhi) ? sp[(size_t)blk * SEGW + lane] : INVALID_PK;
    for (; blk < bhi; blk += 16) {
        const int nb = blk + 16;
        const unsigned int nx = (nb < bhi) ? sp[(size_t)nb * SEGW + lane] : INVALID_PK;
        const int rl = (int)(pk >> 17);
        if (rl < SLICEN) {
            const int c = (int)(pk & 0x1ffffu);
            const int pos = atomicAdd(&cur[rl], 1);
            const int r = s * SLICEN + rl;
            if (pos < ELLW) {
                colell[r * ELLW + pos] = c;
            } else {
                const int a = atomicAdd(auxcnt, 1);
                if (a < AUXCAP) aux[a] = make_int2(r, c);
            }
        }
        pk = nx;
    }
}

// Split: one wave per node. Reorder the ELL row into [c<HALF | c>=HALF] via
// ballot+popcount (reads complete into regs before any write; lockstep wave).
// Repack degc = m | (nlo<<8), m = min(deg, ELLW). Enables the phase-split agg:
// phase-lo gathers target rows < HALF (3.2MB < 4MB XCD L2 -> L2-resident ->
// gather fabric transactions ~vanish; R9 evidence: agg sits at the ~47G/s
// random-transaction ceiling shared with R1's ell_fill).
__global__ __launch_bounds__(256) void ell_split_kernel(int* __restrict__ colell,
                                                        int* __restrict__ degc) {
    const int n = (blockIdx.x * blockDim.x + threadIdx.x) >> 6;
    if (n >= NN) return;
    const int l = threadIdx.x & 63;
    const int m = min(degc[n], ELLW);
    const int c = (l < m) ? colell[n * ELLW + l] : 0;
    const bool valid = l < m;
    const unsigned long long lomask = __ballot(valid && (c < HALF));
    const unsigned long long himask = __ballot(valid && (c >= HALF));
    const int nlo = __popcll(lomask);
    const unsigned long long below = (1ull << l) - 1ull;
    if (valid) {
        const int pos = (c < HALF) ? __popcll(lomask & below)
                                   : nlo + __popcll(himask & below);
        colell[n * ELLW + pos] = c;
    }
    if (l == 0) degc[n] = m | (nlo << 8);
}

// ---------- bf16 shadow helpers ----------

__device__ __forceinline__ unsigned int pack2bf(float a, float b) {
    unsigned int ua = __float_as_uint(a);
    unsigned int ub = __float_as_uint(b);
    return ((ua + 0x8000u) >> 16) | (((ub + 0x8000u) >> 16) << 16);
}

__device__ __forceinline__ f32x2 bf2(unsigned int v) {
    f32x2 r;
    r.x = __uint_as_float(v << 16);
    r.y = __uint_as_float(v & 0xffff0000u);
    return r;
}

__global__ __launch_bounds__(256) void tobf16_kernel(const float* __restrict__ h,
                                                     uint2* __restrict__ hb) {
    int i = blockIdx.x * blockDim.x + threadIdx.x;
    if (i < NV4) {
        const f32x4 v = __builtin_nontemporal_load(((const f32x4*)h) + i);
        hb[i] = make_uint2(pack2bf(v.x, v.y), pack2bf(v.z, v.w));
    }
}

// ---------- per-iteration ----------

// one 8-edge subtile: quads hold edges, f2 holds the feature chunk
__device__ __forceinline__ void subtile(uint4 uu, const f32x2* __restrict__ hr2,
                                        f32x2* __restrict__ acc, float& nmax) {
    f32x2 d0 = hr2[0] - bf2(uu.x);
    f32x2 d1 = hr2[1] - bf2(uu.y);
    f32x2 d2 = hr2[2] - bf2(uu.z);
    f32x2 d3 = hr2[3] - bf2(uu.w);
    f32x2 s2 = d0 * d0;
    s2 += d1 * d1;
    s2 += d2 * d2;
    s2 += d3 * d3;
    float s = s2.x + s2.y;
    s += __shfl_xor(s, 1, 32);
    s += __shfl_xor(s, 2, 32);
    const float n = fmaxf(sqrtf(s), 1e-6f);
    nmax = fmaxf(nmax, n);
    const float w = -rsqrtf(n);
    acc[0] += d0 * w;
    acc[1] += d1 * w;
    acc[2] += d2 * w;
    acc[3] += d3 * w;
}

// One 32-lane group per NODE PAIR, phase-split (R10): phase 0 processes slots
// [0, nlo) (targets < HALF), phase 1 slots [nlo, m). Within a phase the gather
// working set is 3.2MB -> L2-resident per XCD -> gathers stop paying fabric
// transactions. Up to 2 subtiles/node preloaded (covers 99.7% at Poisson(8)
// per phase); rare deeper rows via a group-uniform dynamic tail loop.
// colell reads nt + S stores nt: keep streams out of the L2 gather set.
// Invalid slots gather the node's own row (L1-hit, exact-zero contribution).
__global__ __launch_bounds__(256) void agg_kernel(const uint4* __restrict__ hb4,
                                                  const int* __restrict__ degc,
                                                  const int* __restrict__ colell,
                                                  float* __restrict__ S,
                                                  int* __restrict__ maxslots,
                                                  int phase) {
    const int lane = threadIdx.x & 31;
    const int q = lane >> 2;
    const int f2 = lane & 3;
    const int pair = (blockIdx.x * blockDim.x + threadIdx.x) >> 5;
    const int n0 = pair * 2;
    const int n1 = n0 + 1;

    const int v0 = degc[n0];
    const int v1 = degc[n1];
    const int m0 = v0 & 0xff, nlo0 = v0 >> 8;
    const int m1 = v1 & 0xff, nlo1 = v1 >> 8;
    const int b0 = phase ? nlo0 : 0;
    const int e0 = phase ? m0 : nlo0;
    const int b1 = phase ? nlo1 : 0;
    const int e1 = phase ? m1 : nlo1;
    const int t0 = (e0 - b0 + 7) >> 3;           // trips, group-uniform
    const int t1 = (e1 - b1 + 7) >> 3;

    // own rows — independent, issue first (also warm L1 for self-gathers)
    const uint4 hru0 = hb4[n0 * 4 + f2];
    const uint4 hru1 = hb4[n1 * 4 + f2];

    // preload col indices for up to 2 subtiles per node (slot >= e -> self;
    // note slot >= e automatically when j >= trip)
    int c0[2], c1[2];
    #pragma unroll
    for (int j = 0; j < 2; ++j) {
        const int s0 = b0 + 8 * j + q;
        c0[j] = (s0 < e0) ? __builtin_nontemporal_load(&colell[n0 * ELLW + s0]) : n0;
        const int s1 = b1 + 8 * j + q;
        c1[j] = (s1 < e1) ? __builtin_nontemporal_load(&colell[n1 * ELLW + s1]) : n1;
    }
    uint4 u0[2], u1[2];
    if (0 < t0) u0[0] = hb4[c0[0] * 4 + f2];
    if (0 < t1) u1[0] = hb4[c1[0] * 4 + f2];
    if (1 < t0) u0[1] = hb4[c0[1] * 4 + f2];
    if (1 < t1) u1[1] = hb4[c1[1] * 4 + f2];

    f32x2 hr0[4], hr1[4];
    hr0[0] = bf2(hru0.x); hr0[1] = bf2(hru0.y); hr0[2] = bf2(hru0.z); hr0[3] = bf2(hru0.w);
    hr1[0] = bf2(hru1.x); hr1[1] = bf2(hru1.y); hr1[2] = bf2(hru1.z); hr1[3] = bf2(hru1.w);

    f32x2 acc0[4], acc1[4];
    #pragma unroll
    for (int i = 0; i < 4; ++i) {
        acc0[i] = (f32x2){0.0f, 0.0f};
        acc1[i] = (f32x2){0.0f, 0.0f};
    }
    float nmax = 0.0f;

    if (0 < t0) subtile(u0[0], hr0, acc0, nmax);
    if (0 < t1) subtile(u1[0], hr1, acc1, nmax);
    if (1 < t0) subtile(u0[1], hr0, acc0, nmax);
    if (1 < t1) subtile(u1[1], hr1, acc1, nmax);

    // rare deep tails (phase span > 16 edges), group-uniform trips
    for (int j = 2; j < t0; ++j) {
        const int s0 = b0 + 8 * j + q;
        const int c = (s0 < e0) ? __builtin_nontemporal_load(&colell[n0 * ELLW + s0]) : n0;
        subtile(hb4[c * 4 + f2], hr0, acc0, nmax);
    }
    for (int j = 2; j < t1; ++j) {
        const int s1 = b1 + 8 * j + q;
        const int c = (s1 < e1) ? __builtin_nontemporal_load(&colell[n1 * ELLW + s1]) : n1;
        subtile(hb4[c * 4 + f2], hr1, acc1, nmax);
    }

    // cross-quad reduce (quads hold different edges, same feats)
    #pragma unroll
    for (int m = 4; m < 32; m <<= 1) {
        #pragma unroll
        for (int i = 0; i < 4; ++i) {
            acc0[i].x += __shfl_xor(acc0[i].x, m, 32);
            acc0[i].y += __shfl_xor(acc0[i].y, m, 32);
            acc1[i].x += __shfl_xor(acc1[i].x, m, 32);
            acc1[i].y += __shfl_xor(acc1[i].y, m, 32);
        }
    }
    if (q == 0) {
        f32x4* Sv = (f32x4*)S;
        f32x4 a0 = {acc0[0].x, acc0[0].y, acc0[1].x, acc0[1].y};
        f32x4 a1 = {acc0[2].x, acc0[2].y, acc0[3].x, acc0[3].y};
        f32x4 b0v = {acc1[0].x, acc1[0].y, acc1[1].x, acc1[1].y};
        f32x4 b1v = {acc1[2].x, acc1[2].y, acc1[3].x, acc1[3].y};
        if (phase) {                              // accumulate onto phase-lo S
            a0 += Sv[n0 * 8 + f2 * 2];
            a1 += Sv[n0 * 8 + f2 * 2 + 1];
            b0v += Sv[n1 * 8 + f2 * 2];
            b1v += Sv[n1 * 8 + f2 * 2 + 1];
        }
        __builtin_nontemporal_store(a0, Sv + n0 * 8 + f2 * 2);
        __builtin_nontemporal_store(a1, Sv + n0 * 8 + f2 * 2 + 1);
        __builtin_nontemporal_store(b0v, Sv + n1 * 8 + f2 * 2);
        __builtin_nontemporal_store(b1v, Sv + n1 * 8 + f2 * 2 + 1);
    }

    nmax = fmaxf(nmax, __shfl_xor(nmax, 4, 32));
    nmax = fmaxf(nmax, __shfl_xor(nmax, 8, 32));
    nmax = fmaxf(nmax, __shfl_xor(nmax, 16, 32));
    nmax = fmaxf(nmax, __shfl_xor(nmax, 32, 64));
    if ((threadIdx.x & 63) == 0) {
        // positive floats order like ints; 0xAA poison is negative -> loses
        atomicMax(&maxslots[blockIdx.x & (NSLOT - 1)], __float_as_int(nmax));
    }
}

// overflow edges: full per-edge norm + atomic accumulate into S. A.s. empty.
// Runs AFTER both agg phases and BEFORE update.
__global__ __launch_bounds__(256) void aux_kernel(const uint2* __restrict__ hb,
                                                  const int2* __restrict__ aux,
                                                  const int* __restrict__ auxcnt,
                                                  float* __restrict__ S,
                                                  int* __restrict__ maxslots) {
    const int n = min(*auxcnt, AUXCAP);
    for (int i = blockIdx.x * blockDim.x + threadIdx.x; i < n;
         i += gridDim.x * blockDim.x) {
        const int r = aux[i].x;
        const int c = aux[i].y;
        float d[32];
        float s = 0.0f;
        for (int j = 0; j < 8; ++j) {
            const uint2 ur = hb[r * 8 + j];
            const uint2 uc = hb[c * 8 + j];
            float fr[4], fc[4];
            fr[0] = __uint_as_float(ur.x << 16);
            fr[1] = __uint_as_float(ur.x & 0xffff0000u);
            fr[2] = __uint_as_float(ur.y << 16);
            fr[3] = __uint_as_float(ur.y & 0xffff0000u);
            fc[0] = __uint_as_float(uc.x << 16);
            fc[1] = __uint_as_float(uc.x & 0xffff0000u);
            fc[2] = __uint_as_float(uc.y << 16);
            fc[3] = __uint_as_float(uc.y & 0xffff0000u);
            #pragma unroll
            for (int k = 0; k < 4; ++k) {
                d[j * 4 + k] = fr[k] - fc[k];
                s = fmaf(d[j * 4 + k], d[j * 4 + k], s);
            }
        }
        const float nn = fmaxf(sqrtf(s), 1e-6f);
        atomicMax(&maxslots[i & (NSLOT - 1)], __float_as_int(nn));
        const float w = rsqrtf(nn);
        for (int f = 0; f < 32; ++f) atomicAdd(&S[r * DF + f], -d[f] * w);
    }
}

// h_out = h_in - MU*sqrt(M)*S (fp32), plus refresh of the bf16 shadow.
__global__ __launch_bounds__(256) void update_kernel(const float4* __restrict__ hcur,
                                                     float4* __restrict__ hnxt,
                                                     uint2* __restrict__ hb,
                                                     const float4* __restrict__ S,
                                                     const int* __restrict__ slots) {
    const int t = threadIdx.x;
    int v = slots[t];
    #pragma unroll
    for (int m = 32; m > 0; m >>= 1) v = max(v, __shfl_xor(v, m, 64));
    __shared__ int sm[4];
    __shared__ float sscale;
    if ((t & 63) == 0) sm[t >> 6] = v;
    __syncthreads();
    if (t == 0) {
        int bm = max(max(sm[0], sm[1]), max(sm[2], sm[3]));
        sscale = MU * sqrtf(__int_as_float(bm));
    }
    __syncthreads();
    const float scale = sscale;
    const int i = blockIdx.x * blockDim.x + t;
    if (i < NV4) {
        const float4 hv = hcur[i];
        const float4 sv = S[i];
        float4 o;
        o.x = hv.x - scale * sv.x;
        o.y = hv.y - scale * sv.y;
        o.z = hv.z - scale * sv.z;
        o.w = hv.w - scale * sv.w;
        hnxt[i] = o;
        hb[i] = make_uint2(pack2bf(o.x, o.y), pack2bf(o.z, o.w));
    }
}

extern "C" void kernel_launch(void* const* d_in, const int* in_sizes, int n_in,
                              void* d_out, int out_size, void* d_ws, size_t ws_size,
                              hipStream_t stream) {
    const float* h_in = (const float*)d_in[0];
    const int* row = (const int*)d_in[1];
    const int* col = row + NE;
    float* out = (float*)d_out;

    float* S = (float*)d_ws;                         // NN*DF f32   (12.8 MB)
    int* maxslots = (int*)(S + NN * DF);             // KIT*NSLOT
    int* degc = maxslots + KIT * NSLOT;              // NN
    int* auxcnt = degc + NN;                         // 1
    uintptr_t pa = (uintptr_t)(auxcnt + 1);
    pa = (pa + 7) & ~(uintptr_t)7;
    int2* aux = (int2*)pa;                           // AUXCAP      (0.5 MB)
    int* colell = (int*)(aux + AUXCAP);              // NN*ELLW     (14.4 MB)
    uintptr_t p = (uintptr_t)(colell + NN * ELLW);
    p = (p + 15) & ~(uintptr_t)15;
    uint2* hb = (uint2*)p;                           // NN*DF bf16  (6.4 MB)
    // bucket array aliases S (dead until first agg): 8*6250*64*4B = 12.8MB.
    unsigned int* buck = (unsigned int*)S;
    // count/prefix table aliases hb (dead until tobf16, after the build):
    // 8*20*12500*2B = 4MB <= 6.4MB.
    unsigned short* cnt = (unsigned short*)hb;

    const int fb = NSLICE * NSUB;                    // 160 blocks; slice=bid&7
    const int pb = (NN + 255) / 256;                 // 391
    const int sb = (NN * 64 + 255) / 256;            // 25000 (wave per node)
    const int gb = (NN / 2 * 32 + 255) / 256;        // 6250 (2 nodes/group)
    const int ub = (NV4 + 255) / 256;                // 3125

    zero_kernel<<<1, 64, 0, stream>>>(auxcnt, 1);
    ell_part_kernel<<<NBLKA, 256, 0, stream>>>(row, col, buck, auxcnt, aux);
    ell_count_kernel<<<fb, 1024, 0, stream>>>(buck, cnt);
    ell_prefix_kernel<<<pb, 256, 0, stream>>>(cnt, degc);
    ell_place_kernel<<<fb, 1024, 0, stream>>>(buck, cnt, colell, auxcnt, aux);
    ell_split_kernel<<<sb, 256, 0, stream>>>(colell, degc);
    tobf16_kernel<<<ub, 256, 0, stream>>>(h_in, hb);

    for (int it = 0; it < KIT; ++it) {
        const float* cur = (it == 0) ? h_in : out;
        agg_kernel<<<gb, 256, 0, stream>>>((const uint4*)hb, degc, colell, S,
                                           maxslots + it * NSLOT, 0);
        agg_kernel<<<gb, 256, 0, stream>>>((const uint4*)hb, degc, colell, S,
                                           maxslots + it * NSLOT, 1);
        aux_kernel<<<32, 256, 0, stream>>>(hb, aux, auxcnt, S, maxslots + it * NSLOT);
        update_kernel<<<ub, 256, 0, stream>>>((const float4*)cur, (float4*)out, hb,
                                              (const float4*)S,
                                              maxslots + it * NSLOT);
    }
}

// Round 11
// 373.730 us; speedup vs baseline: 1.5733x; 1.5733x over previous
//
#include <hip/hip_runtime.h>

#define NN 100000
#define NE 1600000
#define DF 32
#define KIT 5
#define MU 0.01f
#define NSLOT 256
#define NV4 (NN * DF / 4)
#define ELLW 36
#define AUXCAP 65536
#define NSLICE 8
#define SLICEN (NN / NSLICE)   // 12500 nodes/slice; colell slice 1.8MB fits XCD L2
#define NSUB 32                // scan-blocks per slice: 8*32=256 blocks = all CUs
#define NBLKA (NE / 256)       // 6250 blocks in pass A, exactly 256 edges each
#define SEGW 64                // per-block per-slice segment capacity (mean fill 32)
#define INVALID_PK 0xffffffffu // sentinel: rl-field = 32767 >= SLICEN, never valid

typedef float f32x4 __attribute__((ext_vector_type(4)));
typedef float f32x2 __attribute__((ext_vector_type(2)));

// ---------- one-time ELL build (edge_index is iteration-invariant) ----------

__global__ __launch_bounds__(64) void zero_kernel(int* __restrict__ p, int n) {
    int i = blockIdx.x * blockDim.x + threadIdx.x;
    if (i < n) p[i] = 0;
}

// Pass A: single streaming scan; bin edges into 8 slice-buckets. Zero global
// atomics in the common path: wave ballot -> per-wave per-bucket counts -> LDS
// prefix across the 4 waves -> LDS-staged segments -> fully-coalesced 256B
// segment writes. Unused slots carry INVALID_PK sentinels. Segment overflow
// (P ~ 1e-9/block) spills to aux. Edge packed to 4B: (rl<14b)<<17 | c(17b).
// Bucket array (8*NBLKA*SEGW*4B = 12.8MB) aliases S (dead until first agg).
__global__ __launch_bounds__(256) void ell_part_kernel(const int* __restrict__ row,
                                                       const int* __restrict__ col,
                                                       unsigned int* __restrict__ buck,
                                                       int* __restrict__ auxcnt,
                                                       int2* __restrict__ aux) {
    __shared__ int wcnt[4][8];
    __shared__ int woff[4][8];
    __shared__ unsigned int sseg[8][SEGW];       // 2KB staging
    const int t = threadIdx.x;
    const int w = t >> 6;
    const int lane = t & 63;

    ((unsigned int*)sseg)[t] = INVALID_PK;
    ((unsigned int*)sseg)[t + 256] = INVALID_PK;

    const int e = blockIdx.x * 256 + t;          // grid is exactly NE/256
    int b = 8;                                   // out-of-range bucket if guarded off
    unsigned int packed = INVALID_PK;
    int r = 0, c = 0;
    if (e < NE) {
        r = __builtin_nontemporal_load(&row[e]);
        c = __builtin_nontemporal_load(&col[e]);
        b = r / SLICEN;                          // 0..7
        const int rl = r - b * SLICEN;           // < 12500
        packed = ((unsigned int)rl << 17) | (unsigned int)c;
    }

    int myprefix = 0;
    #pragma unroll
    for (int k = 0; k < 8; ++k) {
        const unsigned long long mk = __ballot(b == k);
        if (lane == 0) wcnt[w][k] = __popcll(mk);
        if (k == b) myprefix = __popcll(mk & ((1ull << lane) - 1ull));
    }
    __syncthreads();
    if (t < 32) {
        const int w2 = t >> 3, k = t & 7;
        int o = 0;
        for (int w3 = 0; w3 < w2; ++w3) o += wcnt[w3][k];
        woff[w2][k] = o;
    }
    __syncthreads();

    if (b < 8) {
        const int pos = woff[w][b] + myprefix;
        if (pos < SEGW) {
            sseg[b][pos] = packed;
        } else {
            const int a = atomicAdd(auxcnt, 1);  // a.s. never
            if (a < AUXCAP) aux[a] = make_int2(r, c);
        }
    }
    __syncthreads();

    // write out 8 segments x 256B, fully coalesced (incl. sentinels)
    #pragma unroll
    for (int k = 0; k < 2; ++k) {
        const int idx = t + k * 256;
        const int bb = idx >> 6;
        const int j = idx & 63;
        buck[((size_t)bb * NBLKA + blockIdx.x) * SEGW + j] = sseg[bb][j];
    }
}

// Pass B1 (count): block (s,j) scans a DISJOINT 1/NSUB range of slice s's
// bucket stream and histograms ALL 12500 slice nodes in LDS. Dump coalesced
// as uint16 into cnt[s][j][r]. Zero global RMWs. NSUB=32 -> 256 blocks =
// every CU busy (R10 trim; 160 blocks left 96 CUs idle).
__global__ __launch_bounds__(1024) void ell_count_kernel(const unsigned int* __restrict__ buck,
                                                         unsigned short* __restrict__ cnt) {
    __shared__ int hist[SLICEN];                 // 50KB
    const int t = threadIdx.x;
    const int s = blockIdx.x & (NSLICE - 1);
    const int j = blockIdx.x >> 3;               // 0..NSUB-1
    const int lane = t & 63;
    const int wid = t >> 6;                      // 0..15
    const int blo = j * NBLKA / NSUB;
    const int bhi = (j + 1) * NBLKA / NSUB;

    for (int i = t; i < SLICEN; i += 1024) hist[i] = 0;
    __syncthreads();

    const unsigned int* sp = buck + (size_t)s * NBLKA * SEGW;
    int blk = blo + wid;
    unsigned int pk = (blk < bhi) ? sp[(size_t)blk * SEGW + lane] : INVALID_PK;
    for (; blk < bhi; blk += 16) {
        const int nb = blk + 16;
        const unsigned int nx = (nb < bhi) ? sp[(size_t)nb * SEGW + lane] : INVALID_PK;
        const int rl = (int)(pk >> 17);          // sentinel -> 32767, fails check
        if (rl < SLICEN) atomicAdd(&hist[rl], 1);
        pk = nx;
    }
    __syncthreads();
    unsigned short* cp = cnt + ((size_t)s * NSUB + j) * SLICEN;
    for (int i = t; i < SLICEN; i += 1024) cp[i] = (unsigned short)hist[i];
}

// Prefix: per node, exclusive scan of the NSUB per-scan-block counts (in
// place, uint16) + write degc = total. All accesses coalesced.
__global__ __launch_bounds__(256) void ell_prefix_kernel(unsigned short* __restrict__ cnt,
                                                         int* __restrict__ degc) {
    const int i = blockIdx.x * blockDim.x + threadIdx.x;
    if (i >= NN) return;
    const int s = i / SLICEN;
    const int rl = i - s * SLICEN;
    unsigned short* cp = cnt + (size_t)s * NSUB * SLICEN + rl;
    int base = 0;
    #pragma unroll
    for (int j = 0; j < NSUB; ++j) {
        const int v = cp[(size_t)j * SLICEN];
        cp[(size_t)j * SLICEN] = (unsigned short)base;
        base += v;
    }
    degc[i] = base;
}

// Pass B2 (place): preload this block's base offsets into LDS cursors,
// rescan own range, slot = ldsAtomicAdd(cursor). colell writes scattered only
// within the XCD-pinned 1.8MB slice -> merged in L2. Spill -> aux.
// Different j-blocks own disjoint slot ranges per node -> no write races.
__global__ __launch_bounds__(1024) void ell_place_kernel(const unsigned int* __restrict__ buck,
                                                         const unsigned short* __restrict__ cnt,
                                                         int* __restrict__ colell,
                                                         int* __restrict__ auxcnt,
                                                         int2* __restrict__ aux) {
    __shared__ int cur[SLICEN];                  // 50KB cursors
    const int t = threadIdx.x;
    const int s = blockIdx.x & (NSLICE - 1);
    const int j = blockIdx.x >> 3;
    const int lane = t & 63;
    const int wid = t >> 6;
    const int blo = j * NBLKA / NSUB;
    const int bhi = (j + 1) * NBLKA / NSUB;

    const unsigned short* cp = cnt + ((size_t)s * NSUB + j) * SLICEN;
    for (int i = t; i < SLICEN; i += 1024) cur[i] = (int)cp[i];
    __syncthreads();

    const unsigned int* sp = buck + (size_t)s * NBLKA * SEGW;
    int blk = blo + wid;
    unsigned int pk = (blk < bhi) ? sp[(size_t)blk * SEGW + lane] : INVALID_PK;
    for (; blk < bhi; blk += 16) {
        const int nb = blk + 16;
        const unsigned int nx = (nb < bhi) ? sp[(size_t)nb * SEGW + lane] : INVALID_PK;
        const int rl = (int)(pk >> 17);
        if (rl < SLICEN) {
            const int c = (int)(pk & 0x1ffffu);
            const int pos = atomicAdd(&cur[rl], 1);
            const int r = s * SLICEN + rl;
            if (pos < ELLW) {
                colell[r * ELLW + pos] = c;
            } else {
                const int a = atomicAdd(auxcnt, 1);
                if (a < AUXCAP) aux[a] = make_int2(r, c);
            }
        }
        pk = nx;
    }
}

// ---------- bf16 shadow helpers ----------

__device__ __forceinline__ unsigned int pack2bf(float a, float b) {
    unsigned int ua = __float_as_uint(a);
    unsigned int ub = __float_as_uint(b);
    return ((ua + 0x8000u) >> 16) | (((ub + 0x8000u) >> 16) << 16);
}

// one uint32 (2 bf16) -> float2; 2 VALU ops for 2 elements
__device__ __forceinline__ f32x2 bf2(unsigned int v) {
    f32x2 r;
    r.x = __uint_as_float(v << 16);
    r.y = __uint_as_float(v & 0xffff0000u);
    return r;
}

__global__ __launch_bounds__(256) void tobf16_kernel(const float* __restrict__ h,
                                                     uint2* __restrict__ hb) {
    int i = blockIdx.x * blockDim.x + threadIdx.x;
    if (i < NV4) {
        const f32x4 v = __builtin_nontemporal_load(((const f32x4*)h) + i);
        hb[i] = make_uint2(pack2bf(v.x, v.y), pack2bf(v.z, v.w));
    }
}

// ---------- per-iteration ----------

// head compute for one node (4 subtiles of 8 edges; quads hold edges, f2
// holds the feature chunk).
__device__ __forceinline__ void node_head(const uint4* __restrict__ u,
                                          const f32x2* __restrict__ hr2,
                                          f32x2* __restrict__ acc, float& nmax) {
    #pragma unroll
    for (int j = 0; j < 4; ++j) {
        f32x2 d0 = hr2[0] - bf2(u[j].x);
        f32x2 d1 = hr2[1] - bf2(u[j].y);
        f32x2 d2 = hr2[2] - bf2(u[j].z);
        f32x2 d3 = hr2[3] - bf2(u[j].w);
        f32x2 s2 = d0 * d0;
        s2 += d1 * d1;
        s2 += d2 * d2;
        s2 += d3 * d3;
        float s = s2.x + s2.y;
        s += __shfl_xor(s, 1, 32);
        s += __shfl_xor(s, 2, 32);
        const float n = fmaxf(sqrtf(s), 1e-6f);
        nmax = fmaxf(nmax, n);
        const float w = -rsqrtf(n);              // acc += d * (-w') folded
        acc[0] += d0 * w;
        acc[1] += d1 * w;
        acc[2] += d2 * w;
        acc[3] += d3 * w;
    }
}

// tail: edges 32..deg-1 (at most one 8-edge step since ELLW=36)
__device__ __forceinline__ void node_tail(const uint4* __restrict__ hb4,
                                          const int* __restrict__ colell, int n,
                                          int deg, int q, int f2,
                                          const f32x2* __restrict__ hr2,
                                          f32x2* __restrict__ acc, float& nmax) {
    for (int k = 32; k < deg; k += 8) {
        const int ei = k + q;
        const int c = (ei < deg) ? colell[n * ELLW + ei] : n;
        const uint4 uu = hb4[c * 4 + f2];
        f32x2 d0 = hr2[0] - bf2(uu.x);
        f32x2 d1 = hr2[1] - bf2(uu.y);
        f32x2 d2 = hr2[2] - bf2(uu.z);
        f32x2 d3 = hr2[3] - bf2(uu.w);
        f32x2 s2 = d0 * d0;
        s2 += d1 * d1;
        s2 += d2 * d2;
        s2 += d3 * d3;
        float s = s2.x + s2.y;
        s += __shfl_xor(s, 1, 32);
        s += __shfl_xor(s, 2, 32);
        const float n2 = fmaxf(sqrtf(s), 1e-6f);
        nmax = fmaxf(nmax, n2);
        const float w = -rsqrtf(n2);
        acc[0] += d0 * w;
        acc[1] += d1 * w;
        acc[2] += d2 * w;
        acc[3] += d3 * w;
    }
}

// One 32-lane group per NODE PAIR — R9-proven shape (42.5us; at the
// ~47G/s random-transaction ceiling per R8/R9/R10 evidence: ILP x2 hurt,
// packed math null, chain-shortening null, L2 phase-split hurt). Each lane
// loads its OWN 4 col indices directly (quad-mates same address -> HW
// broadcast, one 144B row -> L1-served). No launch_bounds min-waves
// (R7 spill lesson).
__global__ __launch_bounds__(256) void agg_kernel(const uint4* __restrict__ hb4,
                                                  const int* __restrict__ degc,
                                                  const int* __restrict__ colell,
                                                  float* __restrict__ S,
                                                  int* __restrict__ maxslots) {
    const int lane = threadIdx.x & 31;
    const int q = lane >> 2;
    const int f2 = lane & 3;
    const int pair = (blockIdx.x * blockDim.x + threadIdx.x) >> 5;
    const int n0 = pair * 2;
    const int n1 = n0 + 1;

    const int d0 = min(degc[n0], ELLW);
    const int d1 = min(degc[n1], ELLW);

    // own rows — independent, issue first
    const uint4 hru0 = hb4[n0 * 4 + f2];
    const uint4 hru1 = hb4[n1 * 4 + f2];

    // per-lane direct col-index loads (edge slot 8j+q), both nodes
    int c0[4], c1[4];
    #pragma unroll
    for (int j = 0; j < 4; ++j) {
        const int e = 8 * j + q;
        c0[j] = (e < d0) ? colell[n0 * ELLW + e] : n0;
        c1[j] = (e < d1) ? colell[n1 * ELLW + e] : n1;
    }

    // gathers — single VMEM dependency level
    uint4 u0[4], u1[4];
    #pragma unroll
    for (int j = 0; j < 4; ++j) u0[j] = hb4[c0[j] * 4 + f2];
    #pragma unroll
    for (int j = 0; j < 4; ++j) u1[j] = hb4[c1[j] * 4 + f2];

    f32x2 hr0[4], hr1[4];
    hr0[0] = bf2(hru0.x); hr0[1] = bf2(hru0.y); hr0[2] = bf2(hru0.z); hr0[3] = bf2(hru0.w);
    hr1[0] = bf2(hru1.x); hr1[1] = bf2(hru1.y); hr1[2] = bf2(hru1.z); hr1[3] = bf2(hru1.w);

    f32x2 acc0[4], acc1[4];
    #pragma unroll
    for (int i = 0; i < 4; ++i) {
        acc0[i] = (f32x2){0.0f, 0.0f};
        acc1[i] = (f32x2){0.0f, 0.0f};
    }
    float nmax = 0.0f;

    node_head(u0, hr0, acc0, nmax);
    node_head(u1, hr1, acc1, nmax);

    // rare tails (deg > 32)
    node_tail(hb4, colell, n0, d0, q, f2, hr0, acc0, nmax);
    node_tail(hb4, colell, n1, d1, q, f2, hr1, acc1, nmax);

    // cross-quad reduce (quads hold different edges, same feats)
    #pragma unroll
    for (int m = 4; m < 32; m <<= 1) {
        #pragma unroll
        for (int i = 0; i < 4; ++i) {
            acc0[i].x += __shfl_xor(acc0[i].x, m, 32);
            acc0[i].y += __shfl_xor(acc0[i].y, m, 32);
            acc1[i].x += __shfl_xor(acc1[i].x, m, 32);
            acc1[i].y += __shfl_xor(acc1[i].y, m, 32);
        }
    }
    if (q == 0) {
        ((float4*)S)[n0 * 8 + f2 * 2] = make_float4(acc0[0].x, acc0[0].y, acc0[1].x, acc0[1].y);
        ((float4*)S)[n0 * 8 + f2 * 2 + 1] = make_float4(acc0[2].x, acc0[2].y, acc0[3].x, acc0[3].y);
        ((float4*)S)[n1 * 8 + f2 * 2] = make_float4(acc1[0].x, acc1[0].y, acc1[1].x, acc1[1].y);
        ((float4*)S)[n1 * 8 + f2 * 2 + 1] = make_float4(acc1[2].x, acc1[2].y, acc1[3].x, acc1[3].y);
    }

    nmax = fmaxf(nmax, __shfl_xor(nmax, 4, 32));
    nmax = fmaxf(nmax, __shfl_xor(nmax, 8, 32));
    nmax = fmaxf(nmax, __shfl_xor(nmax, 16, 32));
    nmax = fmaxf(nmax, __shfl_xor(nmax, 32, 64));
    if ((threadIdx.x & 63) == 0) {
        // positive floats order like ints; 0xAA poison is negative -> loses
        atomicMax(&maxslots[blockIdx.x & (NSLOT - 1)], __float_as_int(nmax));
    }
}

// overflow edges (deg > ELLW or segment spill): full per-edge norm + atomic
// accumulate into S. Almost surely empty; grid-stride guarantees coverage.
// Runs AFTER agg (its plain S stores) and BEFORE update.
__global__ __launch_bounds__(256) void aux_kernel(const uint2* __restrict__ hb,
                                                  const int2* __restrict__ aux,
                                                  const int* __restrict__ auxcnt,
                                                  float* __restrict__ S,
                                                  int* __restrict__ maxslots) {
    const int n = min(*auxcnt, AUXCAP);
    for (int i = blockIdx.x * blockDim.x + threadIdx.x; i < n;
         i += gridDim.x * blockDim.x) {
        const int r = aux[i].x;
        const int c = aux[i].y;
        float d[32];
        float s = 0.0f;
        for (int j = 0; j < 8; ++j) {
            const uint2 ur = hb[r * 8 + j];
            const uint2 uc = hb[c * 8 + j];
            float fr[4], fc[4];
            fr[0] = __uint_as_float(ur.x << 16);
            fr[1] = __uint_as_float(ur.x & 0xffff0000u);
            fr[2] = __uint_as_float(ur.y << 16);
            fr[3] = __uint_as_float(ur.y & 0xffff0000u);
            fc[0] = __uint_as_float(uc.x << 16);
            fc[1] = __uint_as_float(uc.x & 0xffff0000u);
            fc[2] = __uint_as_float(uc.y << 16);
            fc[3] = __uint_as_float(uc.y & 0xffff0000u);
            #pragma unroll
            for (int k = 0; k < 4; ++k) {
                d[j * 4 + k] = fr[k] - fc[k];
                s = fmaf(d[j * 4 + k], d[j * 4 + k], s);
            }
        }
        const float nn = fmaxf(sqrtf(s), 1e-6f);
        atomicMax(&maxslots[i & (NSLOT - 1)], __float_as_int(nn));
        const float w = rsqrtf(nn);
        for (int f = 0; f < 32; ++f) atomicAdd(&S[r * DF + f], -d[f] * w);
    }
}

// h_out = h_in - MU*sqrt(M)*S (fp32), plus refresh of the bf16 shadow.
// writehb=0 on the LAST iteration: that hb write is never read again
// (aux of iter k reads the hb written by update of iter k-1).
__global__ __launch_bounds__(256) void update_kernel(const float4* __restrict__ hcur,
                                                     float4* __restrict__ hnxt,
                                                     uint2* __restrict__ hb,
                                                     const float4* __restrict__ S,
                                                     const int* __restrict__ slots,
                                                     int writehb) {
    const int t = threadIdx.x;
    int v = slots[t];
    #pragma unroll
    for (int m = 32; m > 0; m >>= 1) v = max(v, __shfl_xor(v, m, 64));
    __shared__ int sm[4];
    __shared__ float sscale;
    if ((t & 63) == 0) sm[t >> 6] = v;
    __syncthreads();
    if (t == 0) {
        int bm = max(max(sm[0], sm[1]), max(sm[2], sm[3]));
        sscale = MU * sqrtf(__int_as_float(bm));
    }
    __syncthreads();
    const float scale = sscale;
    const int i = blockIdx.x * blockDim.x + t;
    if (i < NV4) {
        const float4 hv = hcur[i];
        const float4 sv = S[i];
        float4 o;
        o.x = hv.x - scale * sv.x;
        o.y = hv.y - scale * sv.y;
        o.z = hv.z - scale * sv.z;
        o.w = hv.w - scale * sv.w;
        hnxt[i] = o;
        if (writehb) hb[i] = make_uint2(pack2bf(o.x, o.y), pack2bf(o.z, o.w));
    }
}

extern "C" void kernel_launch(void* const* d_in, const int* in_sizes, int n_in,
                              void* d_out, int out_size, void* d_ws, size_t ws_size,
                              hipStream_t stream) {
    const float* h_in = (const float*)d_in[0];
    const int* row = (const int*)d_in[1];
    const int* col = row + NE;
    float* out = (float*)d_out;

    float* S = (float*)d_ws;                         // NN*DF f32   (12.8 MB)
    int* maxslots = (int*)(S + NN * DF);             // KIT*NSLOT
    int* degc = maxslots + KIT * NSLOT;              // NN
    int* auxcnt = degc + NN;                         // 1
    uintptr_t pa = (uintptr_t)(auxcnt + 1);
    pa = (pa + 7) & ~(uintptr_t)7;
    int2* aux = (int2*)pa;                           // AUXCAP      (0.5 MB)
    int* colell = (int*)(aux + AUXCAP);              // NN*ELLW     (14.4 MB)
    uintptr_t p = (uintptr_t)(colell + NN * ELLW);
    p = (p + 15) & ~(uintptr_t)15;
    uint2* hb = (uint2*)p;                           // NN*DF bf16  (6.4 MB)
    // bucket array aliases S (dead until first agg): 8*6250*64*4B = 12.8MB.
    unsigned int* buck = (unsigned int*)S;
    // count/prefix table aliases hb (dead until tobf16, after the build):
    // 8*32*12500*2B = 6.4MB == sizeof(hb) exactly.
    unsigned short* cnt = (unsigned short*)hb;

    const int fb = NSLICE * NSUB;                    // 256 blocks; slice=bid&7
    const int pb = (NN + 255) / 256;                 // 391
    const int gb = (NN / 2 * 32 + 255) / 256;        // 6250 (2 nodes/group)
    const int ub = (NV4 + 255) / 256;                // 3125

    zero_kernel<<<1, 64, 0, stream>>>(auxcnt, 1);
    ell_part_kernel<<<NBLKA, 256, 0, stream>>>(row, col, buck, auxcnt, aux);
    ell_count_kernel<<<fb, 1024, 0, stream>>>(buck, cnt);
    ell_prefix_kernel<<<pb, 256, 0, stream>>>(cnt, degc);
    ell_place_kernel<<<fb, 1024, 0, stream>>>(buck, cnt, colell, auxcnt, aux);
    tobf16_kernel<<<ub, 256, 0, stream>>>(h_in, hb);

    for (int it = 0; it < KIT; ++it) {
        const float* cur = (it == 0) ? h_in : out;
        agg_kernel<<<gb, 256, 0, stream>>>((const uint4*)hb, degc, colell, S,
                                           maxslots + it * NSLOT);
        aux_kernel<<<32, 256, 0, stream>>>(hb, aux, auxcnt, S, maxslots + it * NSLOT);
        update_kernel<<<ub, 256, 0, stream>>>((const float4*)cur, (float4*)out, hb,
                                              (const float4*)S,
                                              maxslots + it * NSLOT,
                                              (it < KIT - 1) ? 1 : 0);
    }
}

// Round 12
// 364.345 us; speedup vs baseline: 1.6138x; 1.0258x over previous
//
#include <hip/hip_runtime.h>

#define NN 100000
#define NE 1600000
#define DF 32
#define KIT 5
#define MU 0.01f
#define NSLOT 256
#define NV4 (NN * DF / 4)
#define ELLW 36
#define AUXCAP 65536
#define NSLICE 8
#define SLICEN (NN / NSLICE)   // 12500 nodes/slice; colell slice 1.8MB fits XCD L2
#define NSUB 32                // scan-blocks per slice: 8*32=256 blocks = all CUs
#define NBLKA (NE / 256)       // 6250 blocks in pass A, exactly 256 edges each
#define SEGW 64                // per-block per-slice segment capacity (mean fill 32)
#define INVALID_PK 0xffffffffu // sentinel: rl-field = 32767 >= SLICEN, never valid
#define DEGFLAG (1 << 16)      // degc bit: node has aux-overflow edges

typedef float f32x4 __attribute__((ext_vector_type(4)));
typedef float f32x2 __attribute__((ext_vector_type(2)));

// ---------- one-time ELL build (edge_index is iteration-invariant) ----------

__global__ __launch_bounds__(64) void zero_kernel(int* __restrict__ p, int n) {
    int i = blockIdx.x * blockDim.x + threadIdx.x;
    if (i < n) p[i] = 0;
}

// Pass A: single streaming scan; bin edges into 8 slice-buckets. Zero global
// atomics in the common path: wave ballot -> per-wave per-bucket counts -> LDS
// prefix across the 4 waves -> LDS-staged segments -> fully-coalesced 256B
// segment writes. Unused slots carry INVALID_PK sentinels. Segment overflow
// (P ~ 1e-9/block) spills to aux. Edge packed to 4B: (rl<14b)<<17 | c(17b).
// Bucket array (8*NBLKA*SEGW*4B = 12.8MB) aliases S (dead until first agg).
__global__ __launch_bounds__(256) void ell_part_kernel(const int* __restrict__ row,
                                                       const int* __restrict__ col,
                                                       unsigned int* __restrict__ buck,
                                                       int* __restrict__ auxcnt,
                                                       int2* __restrict__ aux) {
    __shared__ int wcnt[4][8];
    __shared__ int woff[4][8];
    __shared__ unsigned int sseg[8][SEGW];       // 2KB staging
    const int t = threadIdx.x;
    const int w = t >> 6;
    const int lane = t & 63;

    ((unsigned int*)sseg)[t] = INVALID_PK;
    ((unsigned int*)sseg)[t + 256] = INVALID_PK;

    const int e = blockIdx.x * 256 + t;          // grid is exactly NE/256
    int b = 8;                                   // out-of-range bucket if guarded off
    unsigned int packed = INVALID_PK;
    int r = 0, c = 0;
    if (e < NE) {
        r = __builtin_nontemporal_load(&row[e]);
        c = __builtin_nontemporal_load(&col[e]);
        b = r / SLICEN;                          // 0..7
        const int rl = r - b * SLICEN;           // < 12500
        packed = ((unsigned int)rl << 17) | (unsigned int)c;
    }

    int myprefix = 0;
    #pragma unroll
    for (int k = 0; k < 8; ++k) {
        const unsigned long long mk = __ballot(b == k);
        if (lane == 0) wcnt[w][k] = __popcll(mk);
        if (k == b) myprefix = __popcll(mk & ((1ull << lane) - 1ull));
    }
    __syncthreads();
    if (t < 32) {
        const int w2 = t >> 3, k = t & 7;
        int o = 0;
        for (int w3 = 0; w3 < w2; ++w3) o += wcnt[w3][k];
        woff[w2][k] = o;
    }
    __syncthreads();

    if (b < 8) {
        const int pos = woff[w][b] + myprefix;
        if (pos < SEGW) {
            sseg[b][pos] = packed;
        } else {
            const int a = atomicAdd(auxcnt, 1);  // a.s. never
            if (a < AUXCAP) aux[a] = make_int2(r, c);
        }
    }
    __syncthreads();

    // write out 8 segments x 256B, fully coalesced (incl. sentinels)
    #pragma unroll
    for (int k = 0; k < 2; ++k) {
        const int idx = t + k * 256;
        const int bb = idx >> 6;
        const int j = idx & 63;
        buck[((size_t)bb * NBLKA + blockIdx.x) * SEGW + j] = sseg[bb][j];
    }
}

// Pass B1 (count): block (s,j) scans a DISJOINT 1/NSUB range of slice s's
// bucket stream and histograms ALL 12500 slice nodes in LDS. Dump coalesced
// as uint16 into cnt[s][j][r]. Zero global RMWs. NSUB=32 -> 256 blocks =
// every CU busy.
__global__ __launch_bounds__(1024) void ell_count_kernel(const unsigned int* __restrict__ buck,
                                                         unsigned short* __restrict__ cnt) {
    __shared__ int hist[SLICEN];                 // 50KB
    const int t = threadIdx.x;
    const int s = blockIdx.x & (NSLICE - 1);
    const int j = blockIdx.x >> 3;               // 0..NSUB-1
    const int lane = t & 63;
    const int wid = t >> 6;                      // 0..15
    const int blo = j * NBLKA / NSUB;
    const int bhi = (j + 1) * NBLKA / NSUB;

    for (int i = t; i < SLICEN; i += 1024) hist[i] = 0;
    __syncthreads();

    const unsigned int* sp = buck + (size_t)s * NBLKA * SEGW;
    int blk = blo + wid;
    unsigned int pk = (blk < bhi) ? sp[(size_t)blk * SEGW + lane] : INVALID_PK;
    for (; blk < bhi; blk += 16) {
        const int nb = blk + 16;
        const unsigned int nx = (nb < bhi) ? sp[(size_t)nb * SEGW + lane] : INVALID_PK;
        const int rl = (int)(pk >> 17);          // sentinel -> 32767, fails check
        if (rl < SLICEN) atomicAdd(&hist[rl], 1);
        pk = nx;
    }
    __syncthreads();
    unsigned short* cp = cnt + ((size_t)s * NSUB + j) * SLICEN;
    for (int i = t; i < SLICEN; i += 1024) cp[i] = (unsigned short)hist[i];
}

// Prefix: per node, exclusive scan of the NSUB per-scan-block counts (in
// place, uint16) + write degc = total. All accesses coalesced.
__global__ __launch_bounds__(256) void ell_prefix_kernel(unsigned short* __restrict__ cnt,
                                                         int* __restrict__ degc) {
    const int i = blockIdx.x * blockDim.x + threadIdx.x;
    if (i >= NN) return;
    const int s = i / SLICEN;
    const int rl = i - s * SLICEN;
    unsigned short* cp = cnt + (size_t)s * NSUB * SLICEN + rl;
    int base = 0;
    #pragma unroll
    for (int j = 0; j < NSUB; ++j) {
        const int v = cp[(size_t)j * SLICEN];
        cp[(size_t)j * SLICEN] = (unsigned short)base;
        base += v;
    }
    degc[i] = base;
}

// Pass B2 (place): preload this block's base offsets into LDS cursors,
// rescan own range, slot = ldsAtomicAdd(cursor). colell writes scattered only
// within the XCD-pinned 1.8MB slice -> merged in L2. Spill -> aux.
// Different j-blocks own disjoint slot ranges per node -> no write races.
__global__ __launch_bounds__(1024) void ell_place_kernel(const unsigned int* __restrict__ buck,
                                                         const unsigned short* __restrict__ cnt,
                                                         int* __restrict__ colell,
                                                         int* __restrict__ auxcnt,
                                                         int2* __restrict__ aux) {
    __shared__ int cur[SLICEN];                  // 50KB cursors
    const int t = threadIdx.x;
    const int s = blockIdx.x & (NSLICE - 1);
    const int j = blockIdx.x >> 3;
    const int lane = t & 63;
    const int wid = t >> 6;
    const int blo = j * NBLKA / NSUB;
    const int bhi = (j + 1) * NBLKA / NSUB;

    const unsigned short* cp = cnt + ((size_t)s * NSUB + j) * SLICEN;
    for (int i = t; i < SLICEN; i += 1024) cur[i] = (int)cp[i];
    __syncthreads();

    const unsigned int* sp = buck + (size_t)s * NBLKA * SEGW;
    int blk = blo + wid;
    unsigned int pk = (blk < bhi) ? sp[(size_t)blk * SEGW + lane] : INVALID_PK;
    for (; blk < bhi; blk += 16) {
        const int nb = blk + 16;
        const unsigned int nx = (nb < bhi) ? sp[(size_t)nb * SEGW + lane] : INVALID_PK;
        const int rl = (int)(pk >> 17);
        if (rl < SLICEN) {
            const int c = (int)(pk & 0x1ffffu);
            const int pos = atomicAdd(&cur[rl], 1);
            const int r = s * SLICEN + rl;
            if (pos < ELLW) {
                colell[r * ELLW + pos] = c;
            } else {
                const int a = atomicAdd(auxcnt, 1);
                if (a < AUXCAP) aux[a] = make_int2(r, c);
            }
        }
        pk = nx;
    }
}

// ---------- bf16 shadow helpers ----------

__device__ __forceinline__ unsigned int pack2bf(float a, float b) {
    unsigned int ua = __float_as_uint(a);
    unsigned int ub = __float_as_uint(b);
    return ((ua + 0x8000u) >> 16) | (((ub + 0x8000u) >> 16) << 16);
}

// one uint32 (2 bf16) -> float2; 2 VALU ops for 2 elements
__device__ __forceinline__ f32x2 bf2(unsigned int v) {
    f32x2 r;
    r.x = __uint_as_float(v << 16);
    r.y = __uint_as_float(v & 0xffff0000u);
    return r;
}

// Also performs the one-time aux sweep (R12): for each overflow edge, set the
// row's DEGFLAG in degc and zero its S row. Flagged rows are then handled by
// commutative atomicAdds in agg (owner + aux tail), so the separate per-iter
// aux_kernel launch disappears. Runs after place (aux final) and after S/buck
// is dead. Duplicate rows in aux: idempotent (OR + store-0).
__global__ __launch_bounds__(256) void tobf16_kernel(const float* __restrict__ h,
                                                     uint2* __restrict__ hb,
                                                     const int2* __restrict__ aux,
                                                     const int* __restrict__ auxcnt,
                                                     int* __restrict__ degc,
                                                     float* __restrict__ S) {
    int i = blockIdx.x * blockDim.x + threadIdx.x;
    if (i < NV4) {
        const f32x4 v = __builtin_nontemporal_load(((const f32x4*)h) + i);
        hb[i] = make_uint2(pack2bf(v.x, v.y), pack2bf(v.z, v.w));
    }
    const int nA = min(*auxcnt, AUXCAP);
    for (int a = blockIdx.x * blockDim.x + threadIdx.x; a < nA;
         a += gridDim.x * blockDim.x) {
        const int r = aux[a].x;
        atomicOr(&degc[r], DEGFLAG);
        f32x4* Sv = (f32x4*)S;
        #pragma unroll
        for (int k = 0; k < 8; ++k) Sv[r * 8 + k] = (f32x4){0.f, 0.f, 0.f, 0.f};
    }
}

// ---------- per-iteration ----------

// head compute for one node (4 subtiles of 8 edges; quads hold edges, f2
// holds the feature chunk).
__device__ __forceinline__ void node_head(const uint4* __restrict__ u,
                                          const f32x2* __restrict__ hr2,
                                          f32x2* __restrict__ acc, float& nmax) {
    #pragma unroll
    for (int j = 0; j < 4; ++j) {
        f32x2 d0 = hr2[0] - bf2(u[j].x);
        f32x2 d1 = hr2[1] - bf2(u[j].y);
        f32x2 d2 = hr2[2] - bf2(u[j].z);
        f32x2 d3 = hr2[3] - bf2(u[j].w);
        f32x2 s2 = d0 * d0;
        s2 += d1 * d1;
        s2 += d2 * d2;
        s2 += d3 * d3;
        float s = s2.x + s2.y;
        s += __shfl_xor(s, 1, 32);
        s += __shfl_xor(s, 2, 32);
        const float n = fmaxf(sqrtf(s), 1e-6f);
        nmax = fmaxf(nmax, n);
        const float w = -rsqrtf(n);              // acc += d * (-w') folded
        acc[0] += d0 * w;
        acc[1] += d1 * w;
        acc[2] += d2 * w;
        acc[3] += d3 * w;
    }
}

// tail: edges 32..deg-1 (at most one 8-edge step since ELLW=36)
__device__ __forceinline__ void node_tail(const uint4* __restrict__ hb4,
                                          const int* __restrict__ colell, int n,
                                          int deg, int q, int f2,
                                          const f32x2* __restrict__ hr2,
                                          f32x2* __restrict__ acc, float& nmax) {
    for (int k = 32; k < deg; k += 8) {
        const int ei = k + q;
        const int c = (ei < deg) ? colell[n * ELLW + ei] : n;
        const uint4 uu = hb4[c * 4 + f2];
        f32x2 d0 = hr2[0] - bf2(uu.x);
        f32x2 d1 = hr2[1] - bf2(uu.y);
        f32x2 d2 = hr2[2] - bf2(uu.z);
        f32x2 d3 = hr2[3] - bf2(uu.w);
        f32x2 s2 = d0 * d0;
        s2 += d1 * d1;
        s2 += d2 * d2;
        s2 += d3 * d3;
        float s = s2.x + s2.y;
        s += __shfl_xor(s, 1, 32);
        s += __shfl_xor(s, 2, 32);
        const float n2 = fmaxf(sqrtf(s), 1e-6f);
        nmax = fmaxf(nmax, n2);
        const float w = -rsqrtf(n2);
        acc[0] += d0 * w;
        acc[1] += d1 * w;
        acc[2] += d2 * w;
        acc[3] += d3 * w;
    }
}

// write one node's 8 accumulated floats (q==0 lanes): plain stores for
// normal rows; commutative atomicAdds for FLAGGED rows (S pre-zeroed; aux
// tail also adds -> order-free).
__device__ __forceinline__ void store_node(float* __restrict__ S, int n, int f2,
                                           const f32x2* __restrict__ acc, bool flag) {
    if (!flag) {
        ((float4*)S)[n * 8 + f2 * 2] = make_float4(acc[0].x, acc[0].y, acc[1].x, acc[1].y);
        ((float4*)S)[n * 8 + f2 * 2 + 1] = make_float4(acc[2].x, acc[2].y, acc[3].x, acc[3].y);
    } else {
        float* p = S + n * 32 + f2 * 8;
        atomicAdd(p + 0, acc[0].x);
        atomicAdd(p + 1, acc[0].y);
        atomicAdd(p + 2, acc[1].x);
        atomicAdd(p + 3, acc[1].y);
        atomicAdd(p + 4, acc[2].x);
        atomicAdd(p + 5, acc[2].y);
        atomicAdd(p + 6, acc[3].x);
        atomicAdd(p + 7, acc[3].y);
    }
}

// One 32-lane group per NODE PAIR — R9/R11-proven shape (43us; at the ~47G/s
// random-transaction ceiling per R8/R9/R10 evidence). Each lane loads its OWN
// 4 col indices directly (quad-mates same address -> HW broadcast). R12: aux
// overflow edges are processed in a grid-stride tail here (commutative
// atomicAdds onto pre-zeroed flagged S rows) — removes the per-iter
// aux_kernel launch. a.s. zero iterations. No launch_bounds min-waves
// (R7 spill lesson).
__global__ __launch_bounds__(256) void agg_kernel(const uint4* __restrict__ hb4,
                                                  const int* __restrict__ degc,
                                                  const int* __restrict__ colell,
                                                  float* __restrict__ S,
                                                  int* __restrict__ maxslots,
                                                  const int2* __restrict__ aux,
                                                  const int* __restrict__ auxcnt) {
    const int lane = threadIdx.x & 31;
    const int q = lane >> 2;
    const int f2 = lane & 3;
    const int pair = (blockIdx.x * blockDim.x + threadIdx.x) >> 5;
    const int n0 = pair * 2;
    const int n1 = n0 + 1;

    const int v0 = degc[n0];
    const int v1 = degc[n1];
    const int d0 = min(v0 & 0xffff, ELLW);
    const int d1 = min(v1 & 0xffff, ELLW);

    // own rows — independent, issue first
    const uint4 hru0 = hb4[n0 * 4 + f2];
    const uint4 hru1 = hb4[n1 * 4 + f2];

    // per-lane direct col-index loads (edge slot 8j+q), both nodes
    int c0[4], c1[4];
    #pragma unroll
    for (int j = 0; j < 4; ++j) {
        const int e = 8 * j + q;
        c0[j] = (e < d0) ? colell[n0 * ELLW + e] : n0;
        c1[j] = (e < d1) ? colell[n1 * ELLW + e] : n1;
    }

    // gathers — single VMEM dependency level
    uint4 u0[4], u1[4];
    #pragma unroll
    for (int j = 0; j < 4; ++j) u0[j] = hb4[c0[j] * 4 + f2];
    #pragma unroll
    for (int j = 0; j < 4; ++j) u1[j] = hb4[c1[j] * 4 + f2];

    f32x2 hr0[4], hr1[4];
    hr0[0] = bf2(hru0.x); hr0[1] = bf2(hru0.y); hr0[2] = bf2(hru0.z); hr0[3] = bf2(hru0.w);
    hr1[0] = bf2(hru1.x); hr1[1] = bf2(hru1.y); hr1[2] = bf2(hru1.z); hr1[3] = bf2(hru1.w);

    f32x2 acc0[4], acc1[4];
    #pragma unroll
    for (int i = 0; i < 4; ++i) {
        acc0[i] = (f32x2){0.0f, 0.0f};
        acc1[i] = (f32x2){0.0f, 0.0f};
    }
    float nmax = 0.0f;

    node_head(u0, hr0, acc0, nmax);
    node_head(u1, hr1, acc1, nmax);

    // rare tails (deg > 32)
    node_tail(hb4, colell, n0, d0, q, f2, hr0, acc0, nmax);
    node_tail(hb4, colell, n1, d1, q, f2, hr1, acc1, nmax);

    // cross-quad reduce (quads hold different edges, same feats)
    #pragma unroll
    for (int m = 4; m < 32; m <<= 1) {
        #pragma unroll
        for (int i = 0; i < 4; ++i) {
            acc0[i].x += __shfl_xor(acc0[i].x, m, 32);
            acc0[i].y += __shfl_xor(acc0[i].y, m, 32);
            acc1[i].x += __shfl_xor(acc1[i].x, m, 32);
            acc1[i].y += __shfl_xor(acc1[i].y, m, 32);
        }
    }
    if (q == 0) {
        store_node(S, n0, f2, acc0, (v0 & DEGFLAG) != 0);
        store_node(S, n1, f2, acc1, (v1 & DEGFLAG) != 0);
    }

    nmax = fmaxf(nmax, __shfl_xor(nmax, 4, 32));
    nmax = fmaxf(nmax, __shfl_xor(nmax, 8, 32));
    nmax = fmaxf(nmax, __shfl_xor(nmax, 16, 32));
    nmax = fmaxf(nmax, __shfl_xor(nmax, 32, 64));
    if ((threadIdx.x & 63) == 0) {
        // positive floats order like ints; 0xAA poison is negative -> loses
        atomicMax(&maxslots[blockIdx.x & (NSLOT - 1)], __float_as_int(nmax));
    }

    // aux tail: overflow edges (deg > ELLW or segment spill). a.s. empty.
    // All S writes for these rows (owner above + here) are atomicAdds onto
    // rows zeroed by tobf16/update -> order-free within this kernel.
    const int nA = min(*auxcnt, AUXCAP);
    const uint2* hb2 = (const uint2*)hb4;
    for (int i = blockIdx.x * blockDim.x + threadIdx.x; i < nA;
         i += gridDim.x * blockDim.x) {
        const int r = aux[i].x;
        const int c = aux[i].y;
        float d[32];
        float s = 0.0f;
        for (int j = 0; j < 8; ++j) {
            const uint2 ur = hb2[r * 8 + j];
            const uint2 uc = hb2[c * 8 + j];
            float fr[4], fc[4];
            fr[0] = __uint_as_float(ur.x << 16);
            fr[1] = __uint_as_float(ur.x & 0xffff0000u);
            fr[2] = __uint_as_float(ur.y << 16);
            fr[3] = __uint_as_float(ur.y & 0xffff0000u);
            fc[0] = __uint_as_float(uc.x << 16);
            fc[1] = __uint_as_float(uc.x & 0xffff0000u);
            fc[2] = __uint_as_float(uc.y << 16);
            fc[3] = __uint_as_float(uc.y & 0xffff0000u);
            #pragma unroll
            for (int k = 0; k < 4; ++k) {
                d[j * 4 + k] = fr[k] - fc[k];
                s = fmaf(d[j * 4 + k], d[j * 4 + k], s);
            }
        }
        const float nn = fmaxf(sqrtf(s), 1e-6f);
        atomicMax(&maxslots[i & (NSLOT - 1)], __float_as_int(nn));
        const float w = rsqrtf(nn);
        for (int f = 0; f < 32; ++f) atomicAdd(&S[r * DF + f], -d[f] * w);
    }
}

// h_out = h_in - MU*sqrt(M)*S (fp32), plus refresh of the bf16 shadow.
// writehb=0 on the LAST iteration (that hb write is never read again).
// R12: re-zero FLAGGED rows' S after reading (ready for next agg's adds).
__global__ __launch_bounds__(256) void update_kernel(const float4* __restrict__ hcur,
                                                     float4* __restrict__ hnxt,
                                                     uint2* __restrict__ hb,
                                                     float* __restrict__ S,
                                                     const int* __restrict__ degc,
                                                     const int* __restrict__ slots,
                                                     int writehb) {
    const int t = threadIdx.x;
    int v = slots[t];
    #pragma unroll
    for (int m = 32; m > 0; m >>= 1) v = max(v, __shfl_xor(v, m, 64));
    __shared__ int sm[4];
    __shared__ float sscale;
    if ((t & 63) == 0) sm[t >> 6] = v;
    __syncthreads();
    if (t == 0) {
        int bm = max(max(sm[0], sm[1]), max(sm[2], sm[3]));
        sscale = MU * sqrtf(__int_as_float(bm));
    }
    __syncthreads();
    const float scale = sscale;
    const int i = blockIdx.x * blockDim.x + t;
    if (i < NV4) {
        const float4 hv = hcur[i];
        const float4 sv = ((const float4*)S)[i];
        float4 o;
        o.x = hv.x - scale * sv.x;
        o.y = hv.y - scale * sv.y;
        o.z = hv.z - scale * sv.z;
        o.w = hv.w - scale * sv.w;
        hnxt[i] = o;
        if (writehb) hb[i] = make_uint2(pack2bf(o.x, o.y), pack2bf(o.z, o.w));
        if (degc[i >> 3] & DEGFLAG) {
            ((float4*)S)[i] = make_float4(0.f, 0.f, 0.f, 0.f);
        }
    }
}

extern "C" void kernel_launch(void* const* d_in, const int* in_sizes, int n_in,
                              void* d_out, int out_size, void* d_ws, size_t ws_size,
                              hipStream_t stream) {
    const float* h_in = (const float*)d_in[0];
    const int* row = (const int*)d_in[1];
    const int* col = row + NE;
    float* out = (float*)d_out;

    float* S = (float*)d_ws;                         // NN*DF f32   (12.8 MB)
    int* maxslots = (int*)(S + NN * DF);             // KIT*NSLOT
    int* degc = maxslots + KIT * NSLOT;              // NN
    int* auxcnt = degc + NN;                         // 1
    uintptr_t pa = (uintptr_t)(auxcnt + 1);
    pa = (pa + 7) & ~(uintptr_t)7;
    int2* aux = (int2*)pa;                           // AUXCAP      (0.5 MB)
    int* colell = (int*)(aux + AUXCAP);              // NN*ELLW     (14.4 MB)
    uintptr_t p = (uintptr_t)(colell + NN * ELLW);
    p = (p + 15) & ~(uintptr_t)15;
    uint2* hb = (uint2*)p;                           // NN*DF bf16  (6.4 MB)
    // bucket array aliases S (dead until first agg): 8*6250*64*4B = 12.8MB.
    unsigned int* buck = (unsigned int*)S;
    // count/prefix table aliases hb (dead until tobf16, after the build):
    // 8*32*12500*2B = 6.4MB == sizeof(hb) exactly.
    unsigned short* cnt = (unsigned short*)hb;

    const int fb = NSLICE * NSUB;                    // 256 blocks; slice=bid&7
    const int pb = (NN + 255) / 256;                 // 391
    const int gb = (NN / 2 * 32 + 255) / 256;        // 6250 (2 nodes/group)
    const int ub = (NV4 + 255) / 256;                // 3125

    zero_kernel<<<1, 64, 0, stream>>>(auxcnt, 1);
    ell_part_kernel<<<NBLKA, 256, 0, stream>>>(row, col, buck, auxcnt, aux);
    ell_count_kernel<<<fb, 1024, 0, stream>>>(buck, cnt);
    ell_prefix_kernel<<<pb, 256, 0, stream>>>(cnt, degc);
    ell_place_kernel<<<fb, 1024, 0, stream>>>(buck, cnt, colell, auxcnt, aux);
    tobf16_kernel<<<ub, 256, 0, stream>>>(h_in, hb, aux, auxcnt, degc, S);

    for (int it = 0; it < KIT; ++it) {
        const float* cur = (it == 0) ? h_in : out;
        agg_kernel<<<gb, 256, 0, stream>>>((const uint4*)hb, degc, colell, S,
                                           maxslots + it * NSLOT, aux, auxcnt);
        update_kernel<<<ub, 256, 0, stream>>>((const float4*)cur, (float4*)out, hb,
                                              S, degc, maxslots + it * NSLOT,
                                              (it < KIT - 1) ? 1 : 0);
    }
}